// Round 7
// baseline (915.699 us; speedup 1.0000x reference)
//
#include <hip/hip_runtime.h>
#include <hip/hip_bf16.h>

// ---------------------------------------------------------------------------
// Swin WindowAttention fused kernel, v7: 4-wave blocks, 2 heads per wave.
//   - 256-thr blocks -> 4 blocks/CU (VGPR cap 128, LDS 32K): 4 independent
//     barrier groups overlap each other's stalls (R1-R6 evidence: 8-wave
//     blocks averaged only ~8 resident waves; phases serialized on latency).
//   - wave w owns heads {w, w+4} sequentially; NO barrier between h0's attn
//     and h1's QKV -> cross-phase ILP within the wave.
//   - attn-out of both heads held in 32 VGPR until one barrier, then -> xs.
//   - proj: each wave computes 64 cols, 4-wide weight-load batches.
//   - all v6 techniques kept: batched loads, sb/sm split tables, identity-
//     MFMA transposes, swapped-operand scores, setprio on attn MFMAs.
//   - __launch_bounds__(256,4): arg2 = min BLOCKS/CU on this toolchain.
// ---------------------------------------------------------------------------

#define NTOK 49
static constexpr float SCALE_Q = 0.17677669529663687f; // 32^-0.5

using bf16   = __bf16;
using bf16x4 = __attribute__((ext_vector_type(4))) __bf16;
using bf16x8 = __attribute__((ext_vector_type(8))) __bf16;
using short4v = __attribute__((ext_vector_type(4))) short;
using f32x4  = __attribute__((ext_vector_type(4))) float;

#define WT_QKV_OFF 0
#define WT_PROJ_OFF (768 * 256 * 2)
#define SB_OFF (WT_PROJ_OFF + 256 * 256 * 2)
#define SM_OFF (SB_OFF + 8 * 4096 * 4)
#define WS_NEEDED (SM_OFF + (size_t)64 * 4096 * 4)

// ---- 16x16x16 bf16 MFMA wrapper (builtin-name portability) ----
static __device__ __forceinline__ f32x4 mfma16(bf16x4 a, bf16x4 b, f32x4 c) {
#if __has_builtin(__builtin_amdgcn_mfma_f32_16x16x16_bf16)
    return __builtin_amdgcn_mfma_f32_16x16x16_bf16(a, b, c, 0, 0, 0);
#elif __has_builtin(__builtin_amdgcn_mfma_f32_16x16x16bf16_1k)
    return __builtin_amdgcn_mfma_f32_16x16x16bf16_1k(
        __builtin_bit_cast(short4v, a), __builtin_bit_cast(short4v, b), c, 0, 0, 0);
#elif __has_builtin(__builtin_amdgcn_mfma_f32_16x16x16_bf16_1k)
    return __builtin_amdgcn_mfma_f32_16x16x16_bf16_1k(
        __builtin_bit_cast(short4v, a), __builtin_bit_cast(short4v, b), c, 0, 0, 0);
#else
    asm volatile("v_mfma_f32_16x16x16_bf16 %0, %1, %2, %0\n\t"
                 "s_nop 7\n\ts_nop 7\n\ts_nop 1"
                 : "+v"(c) : "v"(a), "v"(b));
    return c;
#endif
}

// ---- precompute kernels ----
__global__ void prep_wqkv(const float* __restrict__ qkv_w, bf16* __restrict__ wt) {
    int idx = blockIdx.x * 256 + threadIdx.x;            // 768*256
    if (idx >= 768 * 256) return;
    int n = idx >> 8, k = idx & 255;
    float v = qkv_w[k * 768 + n];
    if (n < 256) v *= SCALE_Q;                           // fold q-scale
    wt[idx] = (bf16)v;                                   // wt[n][k]
}
__global__ void prep_wproj(const float* __restrict__ proj_w, bf16* __restrict__ wt) {
    int idx = blockIdx.x * 256 + threadIdx.x;            // 256*256
    if (idx >= 256 * 256) return;
    int n = idx >> 8, k = idx & 255;
    wt[idx] = (bf16)proj_w[k * 256 + n];                 // wt[n][k]
}
// sb[h][qp][lane][r]: rel-bias part for q=16qt+(lane&15), key=16kt+4*(lane>>4)+r
// (qp = kt*4+qt). -1e30 for key>=49 (pad); 0 for q>=49 (dead rows).
__global__ void prep_sb(const float* __restrict__ bias_table, const int* __restrict__ rel_index,
                        float* __restrict__ sb) {
    int idx = blockIdx.x * 256 + threadIdx.x;            // 8*4096
    if (idx >= 8 * 4096) return;
    int r    = idx & 3;
    int lane = (idx >> 2) & 63;
    int qp   = (idx >> 8) & 15;
    int h    = idx >> 12;
    int kt = qp >> 2, qt = qp & 3;
    int i = qt * 16 + (lane & 15);
    int j = kt * 16 + (lane >> 4) * 4 + r;
    float v;
    if (j >= NTOK)      v = -1e30f;
    else if (i >= NTOK) v = 0.0f;
    else v = bias_table[rel_index[i * 49 + j] * 8 + h];
    sb[idx] = v;
}
// sm[w][qp][lane][r]: window-mask part (0 on padded rows/cols).
__global__ void prep_sm(const float* __restrict__ mask, float* __restrict__ sm) {
    int idx = blockIdx.x * 256 + threadIdx.x;            // 64*4096
    if (idx >= 64 * 4096) return;
    int r    = idx & 3;
    int lane = (idx >> 2) & 63;
    int qp   = (idx >> 8) & 15;
    int w    = idx >> 12;
    int kt = qp >> 2, qt = qp & 3;
    int i = qt * 16 + (lane & 15);
    int j = kt * 16 + (lane >> 4) * 4 + r;
    sm[idx] = (i < NTOK && j < NTOK) ? mask[(w * 49 + i) * 49 + j] : 0.0f;
}

__global__ __launch_bounds__(256, 4) void fused_attn(
    const float* __restrict__ x,
    const float* __restrict__ qkv_b,
    const float* __restrict__ proj_b,
    const bf16* __restrict__ wt_qkv,
    const bf16* __restrict__ wt_proj,
    const float* __restrict__ sb,
    const float* __restrict__ sm,
    float* __restrict__ out)
{
    __shared__ char xs[32768];       // x tile (bf16, swizzled); later attn-out
    const int b    = blockIdx.x;
    const int tid  = threadIdx.x;
    const int lane = tid & 63;
    const int wv   = tid >> 6;       // wave id 0..3; owns heads wv, wv+4
    const int c    = lane & 15;
    const int g    = lane >> 4;

    // ---- stage x -> xs: 2 batches of 8 reg-loads, then cvt+write ----
    {
        const float* xb = x + (size_t)b * (NTOK * 256);
        #pragma unroll
        for (int bt = 0; bt < 2; ++bt) {
            float4 xr[8];
            #pragma unroll
            for (int it = 0; it < 8; ++it) {
                int idx = bt * 2048 + it * 256 + tid;   // 64 rows x 64 chunks
                int row = idx >> 6, c4 = idx & 63;
                xr[it] = make_float4(0.f, 0.f, 0.f, 0.f);
                if (row < NTOK) xr[it] = ((const float4*)xb)[row * 64 + c4];
            }
            #pragma unroll
            for (int it = 0; it < 8; ++it) {
                int idx = bt * 2048 + it * 256 + tid;
                int row = idx >> 6, c4 = idx & 63;
                bf16x4 o;
                o[0] = (bf16)xr[it].x; o[1] = (bf16)xr[it].y;
                o[2] = (bf16)xr[it].z; o[3] = (bf16)xr[it].w;
                *(bf16x4*)(xs + row * 512 + ((c4 * 8) ^ ((row & 7) << 4))) = o;
            }
        }
    }
    __syncthreads();

    // identity B-fragment for the transpose-MFMA: B[k][col] = (k==col)
    bf16x4 iden;
    #pragma unroll
    for (int j = 0; j < 4; ++j) iden[j] = (bf16)((4 * g + j == c) ? 1.0f : 0.0f);

    bf16x4 ob[2][2][4];   // attn-out frags [hh][dt][qt], parked until barrier

    #pragma unroll
    for (int hh = 0; hh < 2; ++hh) {
        const int h = wv + hh * 4;

        bf16x4 qf[4][2];   // [qt][ct]  B-frag for scores
        bf16x4 kf[4][2];   // [kt][ct]  A-frag for scores
        bf16x4 vf[2][4];   // [dt][kt]  A-frag for PV

        // ---- pass QK: [64x256]@[256x64], weight loads batched 4-wide ----
        {
            f32x4 acc[4][4];
            #pragma unroll
            for (int ni = 0; ni < 4; ++ni)
                #pragma unroll
                for (int mi = 0; mi < 4; ++mi)
                    acc[ni][mi] = (f32x4){0.f, 0.f, 0.f, 0.f};

            #pragma unroll
            for (int kk = 0; kk < 8; ++kk) {
                bf16x8 bb[4];
                #pragma unroll
                for (int ni = 0; ni < 4; ++ni) {
                    int ncol = (ni >> 1) * 256 + h * 32 + (ni & 1) * 16 + c;
                    bb[ni] = *(const bf16x8*)(wt_qkv + ncol * 256 + kk * 32 + g * 8);
                }
                bf16x8 a[4];
                #pragma unroll
                for (int mi = 0; mi < 4; ++mi) {
                    int row = mi * 16 + c;
                    a[mi] = *(const bf16x8*)(xs + row * 512 + ((kk * 64 + g * 16) ^ ((row & 7) << 4)));
                }
                #pragma unroll
                for (int ni = 0; ni < 4; ++ni)
                    #pragma unroll
                    for (int mi = 0; mi < 4; ++mi)
                        acc[ni][mi] = __builtin_amdgcn_mfma_f32_16x16x32_bf16(a[mi], bb[ni], acc[ni][mi], 0, 0, 0);
            }
            // +bias, pack bf16, in-register transpose via identity-MFMA
            #pragma unroll
            for (int ni = 0; ni < 4; ++ni) {
                int col = (ni >> 1) * 256 + h * 32 + (ni & 1) * 16 + c;
                float bias = qkv_b[col];
                if (ni < 2) bias *= SCALE_Q;
                #pragma unroll
                for (int mi = 0; mi < 4; ++mi) {
                    bf16x4 in;
                    #pragma unroll
                    for (int r = 0; r < 4; ++r) in[r] = (bf16)(acc[ni][mi][r] + bias);
                    f32x4 t = mfma16(in, iden, (f32x4){0.f, 0.f, 0.f, 0.f});
                    bf16x4 o;
                    #pragma unroll
                    for (int r = 0; r < 4; ++r) o[r] = (bf16)t[r];
                    if (ni < 2) qf[mi][ni] = o;
                    else        kf[mi][ni - 2] = o;
                }
            }
        }

        // ---- pass V: [64x256]@[256x32], loads batched 2-wide ----
        {
            f32x4 acc[2][4];
            #pragma unroll
            for (int dt = 0; dt < 2; ++dt)
                #pragma unroll
                for (int mi = 0; mi < 4; ++mi)
                    acc[dt][mi] = (f32x4){0.f, 0.f, 0.f, 0.f};

            #pragma unroll
            for (int kk = 0; kk < 8; ++kk) {
                bf16x8 bv[2];
                #pragma unroll
                for (int dt = 0; dt < 2; ++dt) {
                    int ncol = 512 + h * 32 + dt * 16 + c;
                    bv[dt] = *(const bf16x8*)(wt_qkv + ncol * 256 + kk * 32 + g * 8);
                }
                bf16x8 a[4];
                #pragma unroll
                for (int mi = 0; mi < 4; ++mi) {
                    int row = mi * 16 + c;
                    a[mi] = *(const bf16x8*)(xs + row * 512 + ((kk * 64 + g * 16) ^ ((row & 7) << 4)));
                }
                #pragma unroll
                for (int dt = 0; dt < 2; ++dt)
                    #pragma unroll
                    for (int mi = 0; mi < 4; ++mi)
                        acc[dt][mi] = __builtin_amdgcn_mfma_f32_16x16x32_bf16(a[mi], bv[dt], acc[dt][mi], 0, 0, 0);
            }
            #pragma unroll
            for (int dt = 0; dt < 2; ++dt) {
                float vb = qkv_b[512 + h * 32 + dt * 16 + c];
                #pragma unroll
                for (int kt = 0; kt < 4; ++kt)
                    #pragma unroll
                    for (int r = 0; r < 4; ++r) vf[dt][kt][r] = (bf16)(acc[dt][kt][r] + vb);
            }
        }

        // ---- attention for this head (registers only; no xs access) ----
        const float* sbh = sb + (size_t)h * 4096;
        const float* smw = sm + (size_t)(b & 63) * 4096;
        #pragma unroll
        for (int qt = 0; qt < 4; ++qt) {
            f32x4 sbv[4], smv[4];
            #pragma unroll
            for (int kt = 0; kt < 4; ++kt)
                sbv[kt] = *(const f32x4*)(sbh + (kt * 4 + qt) * 256 + lane * 4);
            #pragma unroll
            for (int kt = 0; kt < 4; ++kt)
                smv[kt] = *(const f32x4*)(smw + (kt * 4 + qt) * 256 + lane * 4);

            f32x4 sT[4];
            __builtin_amdgcn_s_setprio(1);
            #pragma unroll
            for (int kt = 0; kt < 4; ++kt) {
                sT[kt] = (f32x4){0.f, 0.f, 0.f, 0.f};
                sT[kt] = mfma16(kf[kt][0], qf[qt][0], sT[kt]);
                sT[kt] = mfma16(kf[kt][1], qf[qt][1], sT[kt]);
            }
            __builtin_amdgcn_s_setprio(0);
            #pragma unroll
            for (int kt = 0; kt < 4; ++kt)
                #pragma unroll
                for (int r = 0; r < 4; ++r)
                    sT[kt][r] += sbv[kt][r] + smv[kt][r];
            // softmax over 64 keys: 16 in-lane + reduce across 4 g-lanes
            float m = sT[0][0];
            #pragma unroll
            for (int kt = 0; kt < 4; ++kt)
                #pragma unroll
                for (int r = 0; r < 4; ++r) m = fmaxf(m, sT[kt][r]);
            m = fmaxf(m, __shfl_xor(m, 16));
            m = fmaxf(m, __shfl_xor(m, 32));
            float sum = 0.f;
            #pragma unroll
            for (int kt = 0; kt < 4; ++kt)
                #pragma unroll
                for (int r = 0; r < 4; ++r) {
                    float e = __expf(sT[kt][r] - m);
                    sT[kt][r] = e;
                    sum += e;
                }
            sum += __shfl_xor(sum, 16);
            sum += __shfl_xor(sum, 32);
            float rs = 1.f / sum;
            bf16x4 pB[4];
            #pragma unroll
            for (int kt = 0; kt < 4; ++kt)
                #pragma unroll
                for (int r = 0; r < 4; ++r) pB[kt][r] = (bf16)(sT[kt][r] * rs);
            // PV; park result in ob (no LDS write yet)
            __builtin_amdgcn_s_setprio(1);
            #pragma unroll
            for (int dt = 0; dt < 2; ++dt) {
                f32x4 oT = (f32x4){0.f, 0.f, 0.f, 0.f};
                #pragma unroll
                for (int kt = 0; kt < 4; ++kt)
                    oT = mfma16(vf[dt][kt], pB[kt], oT);
                #pragma unroll
                for (int r = 0; r < 4; ++r) ob[hh][dt][qt][r] = (bf16)oT[r];
            }
            __builtin_amdgcn_s_setprio(0);
        }
    }
    __syncthreads();   // all xs reads (both heads, all waves) done

    // ---- write both heads' attn-out -> xs ----
    #pragma unroll
    for (int hh = 0; hh < 2; ++hh) {
        int h = wv + hh * 4;
        #pragma unroll
        for (int qt = 0; qt < 4; ++qt) {
            int row = qt * 16 + c;
            #pragma unroll
            for (int dt = 0; dt < 2; ++dt) {
                int cbyte = h * 64 + dt * 32 + g * 8;
                *(bf16x4*)(xs + row * 512 + (cbyte ^ ((row & 7) << 4))) = ob[hh][dt][qt];
            }
        }
    }
    __syncthreads();

    // ---- proj: [64x256] @ [256x64] per wave, loads batched 4-wide ----
    {
        f32x4 po[4][4];
        #pragma unroll
        for (int ni = 0; ni < 4; ++ni)
            #pragma unroll
            for (int mi = 0; mi < 4; ++mi)
                po[ni][mi] = (f32x4){0.f, 0.f, 0.f, 0.f};

        #pragma unroll
        for (int kk = 0; kk < 8; ++kk) {
            bf16x8 bw[4];
            #pragma unroll
            for (int ni = 0; ni < 4; ++ni) {
                int col = wv * 64 + ni * 16 + c;
                bw[ni] = *(const bf16x8*)(wt_proj + col * 256 + kk * 32 + g * 8);
            }
            bf16x8 a[4];
            #pragma unroll
            for (int mi = 0; mi < 4; ++mi) {
                int row = mi * 16 + c;
                a[mi] = *(const bf16x8*)(xs + row * 512 + ((kk * 64 + g * 16) ^ ((row & 7) << 4)));
            }
            #pragma unroll
            for (int ni = 0; ni < 4; ++ni)
                #pragma unroll
                for (int mi = 0; mi < 4; ++mi)
                    po[ni][mi] = __builtin_amdgcn_mfma_f32_16x16x32_bf16(a[mi], bw[ni], po[ni][mi], 0, 0, 0);
        }
        float* outb = out + (size_t)b * (NTOK * 256);
        #pragma unroll
        for (int ni = 0; ni < 4; ++ni) {
            int col = wv * 64 + ni * 16 + c;
            float pb = proj_b[col];
            #pragma unroll
            for (int mi = 0; mi < 4; ++mi) {
                #pragma unroll
                for (int r = 0; r < 4; ++r) {
                    int row = mi * 16 + g * 4 + r;
                    if (row < NTOK) outb[row * 256 + col] = po[ni][mi][r] + pb;
                }
            }
        }
    }
}

extern "C" void kernel_launch(void* const* d_in, const int* in_sizes, int n_in,
                              void* d_out, int out_size, void* d_ws, size_t ws_size,
                              hipStream_t stream) {
    const float* x          = (const float*)d_in[0];
    const float* mask       = (const float*)d_in[1];
    const float* qkv_w      = (const float*)d_in[2];
    const float* qkv_b      = (const float*)d_in[3];
    const float* proj_w     = (const float*)d_in[4];
    const float* proj_b     = (const float*)d_in[5];
    const float* bias_table = (const float*)d_in[6];
    const int*   rel_index  = (const int*)d_in[7];
    float* out = (float*)d_out;

    if (ws_size < WS_NEEDED) return;  // needs ~1.7 MB scratch

    char* ws = (char*)d_ws;
    bf16*  wt_qkv  = (bf16*)(ws + WT_QKV_OFF);
    bf16*  wt_proj = (bf16*)(ws + WT_PROJ_OFF);
    float* sbp     = (float*)(ws + SB_OFF);
    float* smp     = (float*)(ws + SM_OFF);

    prep_wqkv <<<768, 256, 0, stream>>>(qkv_w, wt_qkv);
    prep_wproj<<<256, 256, 0, stream>>>(proj_w, wt_proj);
    prep_sb   <<<128, 256, 0, stream>>>(bias_table, rel_index, sbp);
    prep_sm   <<<1024, 256, 0, stream>>>(mask, smp);

    fused_attn<<<4096, 256, 0, stream>>>(x, qkv_b, proj_b, wt_qkv, wt_proj, sbp, smp, out);
}

// Round 8
// 374.619 us; speedup vs baseline: 2.4444x; 2.4444x over previous
//
#include <hip/hip_runtime.h>
#include <hip/hip_bf16.h>

// ---------------------------------------------------------------------------
// Swin WindowAttention fused kernel, v8 = v7 structure, spill-free regime.
//   - __launch_bounds__(256,2): empirical law VGPR cap = 256/arg2 (R2/R7
//     evidence: arg2=4 -> 64 regs -> 2.4GB spill). Cap 128; residency from
//     actual VGPR: <=128 -> 16 waves/CU = 4 independent 4-wave blocks.
//   - 4-wave blocks, wave owns heads {wv, wv+4} sequentially; ONE barrier
//     pair after attention (ob parked in regs), cross-phase ILP in between.
//   - Q/K/V as separate acc[2][4] passes (peak-reg trim, v3-proven shape);
//     2-wide batched weight loads; sb/sm tables loaded as two 4-wide batches.
//   - identity-MFMA in-register transposes; swapped-operand scores; K=16 PV;
//     setprio around attn MFMAs. LDS 32 KiB.
// ---------------------------------------------------------------------------

#define NTOK 49
static constexpr float SCALE_Q = 0.17677669529663687f; // 32^-0.5

using bf16   = __bf16;
using bf16x4 = __attribute__((ext_vector_type(4))) __bf16;
using bf16x8 = __attribute__((ext_vector_type(8))) __bf16;
using short4v = __attribute__((ext_vector_type(4))) short;
using f32x4  = __attribute__((ext_vector_type(4))) float;

#define WT_QKV_OFF 0
#define WT_PROJ_OFF (768 * 256 * 2)
#define SB_OFF (WT_PROJ_OFF + 256 * 256 * 2)
#define SM_OFF (SB_OFF + 8 * 4096 * 4)
#define WS_NEEDED (SM_OFF + (size_t)64 * 4096 * 4)

// ---- 16x16x16 bf16 MFMA wrapper (builtin-name portability) ----
static __device__ __forceinline__ f32x4 mfma16(bf16x4 a, bf16x4 b, f32x4 c) {
#if __has_builtin(__builtin_amdgcn_mfma_f32_16x16x16_bf16)
    return __builtin_amdgcn_mfma_f32_16x16x16_bf16(a, b, c, 0, 0, 0);
#elif __has_builtin(__builtin_amdgcn_mfma_f32_16x16x16bf16_1k)
    return __builtin_amdgcn_mfma_f32_16x16x16bf16_1k(
        __builtin_bit_cast(short4v, a), __builtin_bit_cast(short4v, b), c, 0, 0, 0);
#elif __has_builtin(__builtin_amdgcn_mfma_f32_16x16x16_bf16_1k)
    return __builtin_amdgcn_mfma_f32_16x16x16_bf16_1k(
        __builtin_bit_cast(short4v, a), __builtin_bit_cast(short4v, b), c, 0, 0, 0);
#else
    asm volatile("v_mfma_f32_16x16x16_bf16 %0, %1, %2, %0\n\t"
                 "s_nop 7\n\ts_nop 7\n\ts_nop 1"
                 : "+v"(c) : "v"(a), "v"(b));
    return c;
#endif
}

// ---- precompute kernels ----
__global__ void prep_wqkv(const float* __restrict__ qkv_w, bf16* __restrict__ wt) {
    int idx = blockIdx.x * 256 + threadIdx.x;            // 768*256
    if (idx >= 768 * 256) return;
    int n = idx >> 8, k = idx & 255;
    float v = qkv_w[k * 768 + n];
    if (n < 256) v *= SCALE_Q;                           // fold q-scale
    wt[idx] = (bf16)v;                                   // wt[n][k]
}
__global__ void prep_wproj(const float* __restrict__ proj_w, bf16* __restrict__ wt) {
    int idx = blockIdx.x * 256 + threadIdx.x;            // 256*256
    if (idx >= 256 * 256) return;
    int n = idx >> 8, k = idx & 255;
    wt[idx] = (bf16)proj_w[k * 256 + n];                 // wt[n][k]
}
// sb[h][qp][lane][r]: rel-bias part for q=16qt+(lane&15), key=16kt+4*(lane>>4)+r
// (qp = kt*4+qt). -1e30 for key>=49 (pad); 0 for q>=49 (dead rows).
__global__ void prep_sb(const float* __restrict__ bias_table, const int* __restrict__ rel_index,
                        float* __restrict__ sb) {
    int idx = blockIdx.x * 256 + threadIdx.x;            // 8*4096
    if (idx >= 8 * 4096) return;
    int r    = idx & 3;
    int lane = (idx >> 2) & 63;
    int qp   = (idx >> 8) & 15;
    int h    = idx >> 12;
    int kt = qp >> 2, qt = qp & 3;
    int i = qt * 16 + (lane & 15);
    int j = kt * 16 + (lane >> 4) * 4 + r;
    float v;
    if (j >= NTOK)      v = -1e30f;
    else if (i >= NTOK) v = 0.0f;
    else v = bias_table[rel_index[i * 49 + j] * 8 + h];
    sb[idx] = v;
}
// sm[w][qp][lane][r]: window-mask part (0 on padded rows/cols).
__global__ void prep_sm(const float* __restrict__ mask, float* __restrict__ sm) {
    int idx = blockIdx.x * 256 + threadIdx.x;            // 64*4096
    if (idx >= 64 * 4096) return;
    int r    = idx & 3;
    int lane = (idx >> 2) & 63;
    int qp   = (idx >> 8) & 15;
    int w    = idx >> 12;
    int kt = qp >> 2, qt = qp & 3;
    int i = qt * 16 + (lane & 15);
    int j = kt * 16 + (lane >> 4) * 4 + r;
    sm[idx] = (i < NTOK && j < NTOK) ? mask[(w * 49 + i) * 49 + j] : 0.0f;
}

__global__ __launch_bounds__(256, 2) void fused_attn(
    const float* __restrict__ x,
    const float* __restrict__ qkv_b,
    const float* __restrict__ proj_b,
    const bf16* __restrict__ wt_qkv,
    const bf16* __restrict__ wt_proj,
    const float* __restrict__ sb,
    const float* __restrict__ sm,
    float* __restrict__ out)
{
    __shared__ char xs[32768];       // x tile (bf16, swizzled); later attn-out
    const int b    = blockIdx.x;
    const int tid  = threadIdx.x;
    const int lane = tid & 63;
    const int wv   = tid >> 6;       // wave id 0..3; owns heads wv, wv+4
    const int c    = lane & 15;
    const int g    = lane >> 4;

    // ---- stage x -> xs: 2 batches of 8 reg-loads, then cvt+write ----
    {
        const float* xb = x + (size_t)b * (NTOK * 256);
        #pragma unroll
        for (int bt = 0; bt < 2; ++bt) {
            float4 xr[8];
            #pragma unroll
            for (int it = 0; it < 8; ++it) {
                int idx = bt * 2048 + it * 256 + tid;   // 64 rows x 64 chunks
                int row = idx >> 6, c4 = idx & 63;
                xr[it] = make_float4(0.f, 0.f, 0.f, 0.f);
                if (row < NTOK) xr[it] = ((const float4*)xb)[row * 64 + c4];
            }
            #pragma unroll
            for (int it = 0; it < 8; ++it) {
                int idx = bt * 2048 + it * 256 + tid;
                int row = idx >> 6, c4 = idx & 63;
                bf16x4 o;
                o[0] = (bf16)xr[it].x; o[1] = (bf16)xr[it].y;
                o[2] = (bf16)xr[it].z; o[3] = (bf16)xr[it].w;
                *(bf16x4*)(xs + row * 512 + ((c4 * 8) ^ ((row & 7) << 4))) = o;
            }
        }
    }
    __syncthreads();

    // identity B-fragment for the transpose-MFMA: B[k][col] = (k==col)
    bf16x4 iden;
    #pragma unroll
    for (int j = 0; j < 4; ++j) iden[j] = (bf16)((4 * g + j == c) ? 1.0f : 0.0f);

    bf16x4 ob[2][2][4];   // attn-out frags [hh][dt][qt], parked until barrier

    #pragma unroll
    for (int hh = 0; hh < 2; ++hh) {
        const int h = wv + hh * 4;

        bf16x4 qf[4][2];   // [qt][ct]  B-frag for scores
        bf16x4 kf[4][2];   // [kt][ct]  A-frag for scores
        bf16x4 vf[2][4];   // [dt][kt]  A-frag for PV

        // ---- pass Q: [64x256]@[256x32], 2-wide batched loads ----
        {
            f32x4 acc[2][4];
            #pragma unroll
            for (int ni = 0; ni < 2; ++ni)
                #pragma unroll
                for (int mi = 0; mi < 4; ++mi)
                    acc[ni][mi] = (f32x4){0.f, 0.f, 0.f, 0.f};
            #pragma unroll
            for (int kk = 0; kk < 8; ++kk) {
                bf16x8 bb[2];
                #pragma unroll
                for (int ni = 0; ni < 2; ++ni) {
                    int ncol = h * 32 + ni * 16 + c;
                    bb[ni] = *(const bf16x8*)(wt_qkv + ncol * 256 + kk * 32 + g * 8);
                }
                bf16x8 a[4];
                #pragma unroll
                for (int mi = 0; mi < 4; ++mi) {
                    int row = mi * 16 + c;
                    a[mi] = *(const bf16x8*)(xs + row * 512 + ((kk * 64 + g * 16) ^ ((row & 7) << 4)));
                }
                #pragma unroll
                for (int ni = 0; ni < 2; ++ni)
                    #pragma unroll
                    for (int mi = 0; mi < 4; ++mi)
                        acc[ni][mi] = __builtin_amdgcn_mfma_f32_16x16x32_bf16(a[mi], bb[ni], acc[ni][mi], 0, 0, 0);
            }
            #pragma unroll
            for (int ni = 0; ni < 2; ++ni) {
                float bias = qkv_b[h * 32 + ni * 16 + c] * SCALE_Q;
                #pragma unroll
                for (int mi = 0; mi < 4; ++mi) {
                    bf16x4 in;
                    #pragma unroll
                    for (int r = 0; r < 4; ++r) in[r] = (bf16)(acc[ni][mi][r] + bias);
                    f32x4 t = mfma16(in, iden, (f32x4){0.f, 0.f, 0.f, 0.f});
                    #pragma unroll
                    for (int r = 0; r < 4; ++r) qf[mi][ni][r] = (bf16)t[r];
                }
            }
        }

        // ---- pass K ----
        {
            f32x4 acc[2][4];
            #pragma unroll
            for (int ni = 0; ni < 2; ++ni)
                #pragma unroll
                for (int mi = 0; mi < 4; ++mi)
                    acc[ni][mi] = (f32x4){0.f, 0.f, 0.f, 0.f};
            #pragma unroll
            for (int kk = 0; kk < 8; ++kk) {
                bf16x8 bb[2];
                #pragma unroll
                for (int ni = 0; ni < 2; ++ni) {
                    int ncol = 256 + h * 32 + ni * 16 + c;
                    bb[ni] = *(const bf16x8*)(wt_qkv + ncol * 256 + kk * 32 + g * 8);
                }
                bf16x8 a[4];
                #pragma unroll
                for (int mi = 0; mi < 4; ++mi) {
                    int row = mi * 16 + c;
                    a[mi] = *(const bf16x8*)(xs + row * 512 + ((kk * 64 + g * 16) ^ ((row & 7) << 4)));
                }
                #pragma unroll
                for (int ni = 0; ni < 2; ++ni)
                    #pragma unroll
                    for (int mi = 0; mi < 4; ++mi)
                        acc[ni][mi] = __builtin_amdgcn_mfma_f32_16x16x32_bf16(a[mi], bb[ni], acc[ni][mi], 0, 0, 0);
            }
            #pragma unroll
            for (int ni = 0; ni < 2; ++ni) {
                float bias = qkv_b[256 + h * 32 + ni * 16 + c];
                #pragma unroll
                for (int mi = 0; mi < 4; ++mi) {
                    bf16x4 in;
                    #pragma unroll
                    for (int r = 0; r < 4; ++r) in[r] = (bf16)(acc[ni][mi][r] + bias);
                    f32x4 t = mfma16(in, iden, (f32x4){0.f, 0.f, 0.f, 0.f});
                    #pragma unroll
                    for (int r = 0; r < 4; ++r) kf[mi][ni][r] = (bf16)t[r];
                }
            }
        }

        // ---- pass V (C-frag == PV A-frag, no transform) ----
        {
            f32x4 acc[2][4];
            #pragma unroll
            for (int dt = 0; dt < 2; ++dt)
                #pragma unroll
                for (int mi = 0; mi < 4; ++mi)
                    acc[dt][mi] = (f32x4){0.f, 0.f, 0.f, 0.f};
            #pragma unroll
            for (int kk = 0; kk < 8; ++kk) {
                bf16x8 bv[2];
                #pragma unroll
                for (int dt = 0; dt < 2; ++dt) {
                    int ncol = 512 + h * 32 + dt * 16 + c;
                    bv[dt] = *(const bf16x8*)(wt_qkv + ncol * 256 + kk * 32 + g * 8);
                }
                bf16x8 a[4];
                #pragma unroll
                for (int mi = 0; mi < 4; ++mi) {
                    int row = mi * 16 + c;
                    a[mi] = *(const bf16x8*)(xs + row * 512 + ((kk * 64 + g * 16) ^ ((row & 7) << 4)));
                }
                #pragma unroll
                for (int dt = 0; dt < 2; ++dt)
                    #pragma unroll
                    for (int mi = 0; mi < 4; ++mi)
                        acc[dt][mi] = __builtin_amdgcn_mfma_f32_16x16x32_bf16(a[mi], bv[dt], acc[dt][mi], 0, 0, 0);
            }
            #pragma unroll
            for (int dt = 0; dt < 2; ++dt) {
                float vb = qkv_b[512 + h * 32 + dt * 16 + c];
                #pragma unroll
                for (int kt = 0; kt < 4; ++kt)
                    #pragma unroll
                    for (int r = 0; r < 4; ++r) vf[dt][kt][r] = (bf16)(acc[dt][kt][r] + vb);
            }
        }

        // ---- attention for this head (registers only; no xs access) ----
        const float* sbh = sb + (size_t)h * 4096;
        const float* smw = sm + (size_t)(b & 63) * 4096;
        #pragma unroll
        for (int qt = 0; qt < 4; ++qt) {
            // batch 1: rel-bias vectors (cover with score MFMAs)
            f32x4 sbv[4];
            #pragma unroll
            for (int kt = 0; kt < 4; ++kt)
                sbv[kt] = *(const f32x4*)(sbh + (kt * 4 + qt) * 256 + lane * 4);

            f32x4 sT[4];
            __builtin_amdgcn_s_setprio(1);
            #pragma unroll
            for (int kt = 0; kt < 4; ++kt) {
                sT[kt] = (f32x4){0.f, 0.f, 0.f, 0.f};
                sT[kt] = mfma16(kf[kt][0], qf[qt][0], sT[kt]);
                sT[kt] = mfma16(kf[kt][1], qf[qt][1], sT[kt]);
            }
            __builtin_amdgcn_s_setprio(0);
            // batch 2: mask vectors (issued while sbv adds retire)
            f32x4 smv[4];
            #pragma unroll
            for (int kt = 0; kt < 4; ++kt)
                smv[kt] = *(const f32x4*)(smw + (kt * 4 + qt) * 256 + lane * 4);
            #pragma unroll
            for (int kt = 0; kt < 4; ++kt)
                #pragma unroll
                for (int r = 0; r < 4; ++r)
                    sT[kt][r] += sbv[kt][r] + smv[kt][r];
            // softmax over 64 keys: 16 in-lane + reduce across 4 g-lanes
            float m = sT[0][0];
            #pragma unroll
            for (int kt = 0; kt < 4; ++kt)
                #pragma unroll
                for (int r = 0; r < 4; ++r) m = fmaxf(m, sT[kt][r]);
            m = fmaxf(m, __shfl_xor(m, 16));
            m = fmaxf(m, __shfl_xor(m, 32));
            float sum = 0.f;
            #pragma unroll
            for (int kt = 0; kt < 4; ++kt)
                #pragma unroll
                for (int r = 0; r < 4; ++r) {
                    float e = __expf(sT[kt][r] - m);
                    sT[kt][r] = e;
                    sum += e;
                }
            sum += __shfl_xor(sum, 16);
            sum += __shfl_xor(sum, 32);
            float rs = 1.f / sum;
            bf16x4 pB[4];
            #pragma unroll
            for (int kt = 0; kt < 4; ++kt)
                #pragma unroll
                for (int r = 0; r < 4; ++r) pB[kt][r] = (bf16)(sT[kt][r] * rs);
            // PV; park result in ob (no LDS write yet)
            __builtin_amdgcn_s_setprio(1);
            #pragma unroll
            for (int dt = 0; dt < 2; ++dt) {
                f32x4 oT = (f32x4){0.f, 0.f, 0.f, 0.f};
                #pragma unroll
                for (int kt = 0; kt < 4; ++kt)
                    oT = mfma16(vf[dt][kt], pB[kt], oT);
                #pragma unroll
                for (int r = 0; r < 4; ++r) ob[hh][dt][qt][r] = (bf16)oT[r];
            }
            __builtin_amdgcn_s_setprio(0);
        }
    }
    __syncthreads();   // all xs reads (both heads, all waves) done

    // ---- write both heads' attn-out -> xs ----
    #pragma unroll
    for (int hh = 0; hh < 2; ++hh) {
        int h = wv + hh * 4;
        #pragma unroll
        for (int qt = 0; qt < 4; ++qt) {
            int row = qt * 16 + c;
            #pragma unroll
            for (int dt = 0; dt < 2; ++dt) {
                int cbyte = h * 64 + dt * 32 + g * 8;
                *(bf16x4*)(xs + row * 512 + (cbyte ^ ((row & 7) << 4))) = ob[hh][dt][qt];
            }
        }
    }
    __syncthreads();

    // ---- proj: [64x256] @ [256x64] per wave, loads batched 4-wide ----
    {
        f32x4 po[4][4];
        #pragma unroll
        for (int ni = 0; ni < 4; ++ni)
            #pragma unroll
            for (int mi = 0; mi < 4; ++mi)
                po[ni][mi] = (f32x4){0.f, 0.f, 0.f, 0.f};

        #pragma unroll
        for (int kk = 0; kk < 8; ++kk) {
            bf16x8 bw[4];
            #pragma unroll
            for (int ni = 0; ni < 4; ++ni) {
                int col = wv * 64 + ni * 16 + c;
                bw[ni] = *(const bf16x8*)(wt_proj + col * 256 + kk * 32 + g * 8);
            }
            bf16x8 a[4];
            #pragma unroll
            for (int mi = 0; mi < 4; ++mi) {
                int row = mi * 16 + c;
                a[mi] = *(const bf16x8*)(xs + row * 512 + ((kk * 64 + g * 16) ^ ((row & 7) << 4)));
            }
            #pragma unroll
            for (int ni = 0; ni < 4; ++ni)
                #pragma unroll
                for (int mi = 0; mi < 4; ++mi)
                    po[ni][mi] = __builtin_amdgcn_mfma_f32_16x16x32_bf16(a[mi], bw[ni], po[ni][mi], 0, 0, 0);
        }
        float* outb = out + (size_t)b * (NTOK * 256);
        #pragma unroll
        for (int ni = 0; ni < 4; ++ni) {
            int col = wv * 64 + ni * 16 + c;
            float pb = proj_b[col];
            #pragma unroll
            for (int mi = 0; mi < 4; ++mi) {
                #pragma unroll
                for (int r = 0; r < 4; ++r) {
                    int row = mi * 16 + g * 4 + r;
                    if (row < NTOK) outb[row * 256 + col] = po[ni][mi][r] + pb;
                }
            }
        }
    }
}

extern "C" void kernel_launch(void* const* d_in, const int* in_sizes, int n_in,
                              void* d_out, int out_size, void* d_ws, size_t ws_size,
                              hipStream_t stream) {
    const float* x          = (const float*)d_in[0];
    const float* mask       = (const float*)d_in[1];
    const float* qkv_w      = (const float*)d_in[2];
    const float* qkv_b      = (const float*)d_in[3];
    const float* proj_w     = (const float*)d_in[4];
    const float* proj_b     = (const float*)d_in[5];
    const float* bias_table = (const float*)d_in[6];
    const int*   rel_index  = (const int*)d_in[7];
    float* out = (float*)d_out;

    if (ws_size < WS_NEEDED) return;  // needs ~1.7 MB scratch

    char* ws = (char*)d_ws;
    bf16*  wt_qkv  = (bf16*)(ws + WT_QKV_OFF);
    bf16*  wt_proj = (bf16*)(ws + WT_PROJ_OFF);
    float* sbp     = (float*)(ws + SB_OFF);
    float* smp     = (float*)(ws + SM_OFF);

    prep_wqkv <<<768, 256, 0, stream>>>(qkv_w, wt_qkv);
    prep_wproj<<<256, 256, 0, stream>>>(proj_w, wt_proj);
    prep_sb   <<<128, 256, 0, stream>>>(bias_table, rel_index, sbp);
    prep_sm   <<<1024, 256, 0, stream>>>(mask, smp);

    fused_attn<<<4096, 256, 0, stream>>>(x, qkv_b, proj_b, wt_qkv, wt_proj, sbp, smp, out);
}

// Round 9
// 373.000 us; speedup vs baseline: 2.4550x; 1.0043x over previous
//
#include <hip/hip_runtime.h>
#include <hip/hip_bf16.h>

// ---------------------------------------------------------------------------
// Swin WindowAttention fused kernel, v9: register-disciplined pipeline.
//   - Phase order per head: Q -> K -> scores+softmax(all qt) -> V -> PV.
//     pB (32 regs) parks across V-pass instead of qf+kf (64) -> peak ~112,
//     no spill at the 128 cap (R8's V-pass was ~150 -> scratch traffic).
//   - BK=64 everywhere: 4 iters x {4-wide weight batch + 8 ds_read + 16 MFMA}
//     halves serial global-load exposures per pass.
//   - 512-thr 8-wave blocks, 1 head/wave (v6 topology). LDS 32 KiB.
//   - identity-MFMA in-register transposes; swapped-operand scores; K=16 PV;
//     sb/sm split tables; setprio around attn MFMAs; launch_bounds(512,2)
//     (empirical: VGPR cap = 256/arg2 on this toolchain).
// ---------------------------------------------------------------------------

#define NTOK 49
static constexpr float SCALE_Q = 0.17677669529663687f; // 32^-0.5

using bf16   = __bf16;
using bf16x4 = __attribute__((ext_vector_type(4))) __bf16;
using bf16x8 = __attribute__((ext_vector_type(8))) __bf16;
using short4v = __attribute__((ext_vector_type(4))) short;
using f32x4  = __attribute__((ext_vector_type(4))) float;

#define WT_QKV_OFF 0
#define WT_PROJ_OFF (768 * 256 * 2)
#define SB_OFF (WT_PROJ_OFF + 256 * 256 * 2)
#define SM_OFF (SB_OFF + 8 * 4096 * 4)
#define WS_NEEDED (SM_OFF + (size_t)64 * 4096 * 4)

// ---- 16x16x16 bf16 MFMA wrapper (builtin-name portability) ----
static __device__ __forceinline__ f32x4 mfma16(bf16x4 a, bf16x4 b, f32x4 c) {
#if __has_builtin(__builtin_amdgcn_mfma_f32_16x16x16_bf16)
    return __builtin_amdgcn_mfma_f32_16x16x16_bf16(a, b, c, 0, 0, 0);
#elif __has_builtin(__builtin_amdgcn_mfma_f32_16x16x16bf16_1k)
    return __builtin_amdgcn_mfma_f32_16x16x16bf16_1k(
        __builtin_bit_cast(short4v, a), __builtin_bit_cast(short4v, b), c, 0, 0, 0);
#elif __has_builtin(__builtin_amdgcn_mfma_f32_16x16x16_bf16_1k)
    return __builtin_amdgcn_mfma_f32_16x16x16_bf16_1k(
        __builtin_bit_cast(short4v, a), __builtin_bit_cast(short4v, b), c, 0, 0, 0);
#else
    asm volatile("v_mfma_f32_16x16x16_bf16 %0, %1, %2, %0\n\t"
                 "s_nop 7\n\ts_nop 7\n\ts_nop 1"
                 : "+v"(c) : "v"(a), "v"(b));
    return c;
#endif
}

// ---- precompute kernels ----
__global__ void prep_wqkv(const float* __restrict__ qkv_w, bf16* __restrict__ wt) {
    int idx = blockIdx.x * 256 + threadIdx.x;            // 768*256
    if (idx >= 768 * 256) return;
    int n = idx >> 8, k = idx & 255;
    float v = qkv_w[k * 768 + n];
    if (n < 256) v *= SCALE_Q;                           // fold q-scale
    wt[idx] = (bf16)v;                                   // wt[n][k]
}
__global__ void prep_wproj(const float* __restrict__ proj_w, bf16* __restrict__ wt) {
    int idx = blockIdx.x * 256 + threadIdx.x;            // 256*256
    if (idx >= 256 * 256) return;
    int n = idx >> 8, k = idx & 255;
    wt[idx] = (bf16)proj_w[k * 256 + n];                 // wt[n][k]
}
// sb[h][qp][lane][r]: rel-bias part for q=16qt+(lane&15), key=16kt+4*(lane>>4)+r
// (qp = kt*4+qt). -1e30 for key>=49 (pad); 0 for q>=49 (dead rows).
__global__ void prep_sb(const float* __restrict__ bias_table, const int* __restrict__ rel_index,
                        float* __restrict__ sb) {
    int idx = blockIdx.x * 256 + threadIdx.x;            // 8*4096
    if (idx >= 8 * 4096) return;
    int r    = idx & 3;
    int lane = (idx >> 2) & 63;
    int qp   = (idx >> 8) & 15;
    int h    = idx >> 12;
    int kt = qp >> 2, qt = qp & 3;
    int i = qt * 16 + (lane & 15);
    int j = kt * 16 + (lane >> 4) * 4 + r;
    float v;
    if (j >= NTOK)      v = -1e30f;
    else if (i >= NTOK) v = 0.0f;
    else v = bias_table[rel_index[i * 49 + j] * 8 + h];
    sb[idx] = v;
}
// sm[w][qp][lane][r]: window-mask part (0 on padded rows/cols).
__global__ void prep_sm(const float* __restrict__ mask, float* __restrict__ sm) {
    int idx = blockIdx.x * 256 + threadIdx.x;            // 64*4096
    if (idx >= 64 * 4096) return;
    int r    = idx & 3;
    int lane = (idx >> 2) & 63;
    int qp   = (idx >> 8) & 15;
    int w    = idx >> 12;
    int kt = qp >> 2, qt = qp & 3;
    int i = qt * 16 + (lane & 15);
    int j = kt * 16 + (lane >> 4) * 4 + r;
    sm[idx] = (i < NTOK && j < NTOK) ? mask[(w * 49 + i) * 49 + j] : 0.0f;
}

__global__ __launch_bounds__(512, 2) void fused_attn(
    const float* __restrict__ x,
    const float* __restrict__ qkv_b,
    const float* __restrict__ proj_b,
    const bf16* __restrict__ wt_qkv,
    const bf16* __restrict__ wt_proj,
    const float* __restrict__ sb,
    const float* __restrict__ sm,
    float* __restrict__ out)
{
    __shared__ char xs[32768];       // x tile (bf16, swizzled); later attn-out
    const int b    = blockIdx.x;
    const int tid  = threadIdx.x;
    const int lane = tid & 63;
    const int h    = tid >> 6;       // wave id == head
    const int c    = lane & 15;
    const int g    = lane >> 4;

    // ---- stage x -> xs: 8 reg-loads batched, then cvt+write ----
    {
        const float* xb = x + (size_t)b * (NTOK * 256);
        float4 xr[8];
        #pragma unroll
        for (int it = 0; it < 8; ++it) {
            int idx = it * 512 + tid;          // 64 rows x 64 float4-chunks
            int row = idx >> 6, c4 = idx & 63;
            xr[it] = make_float4(0.f, 0.f, 0.f, 0.f);
            if (row < NTOK) xr[it] = ((const float4*)xb)[row * 64 + c4];
        }
        #pragma unroll
        for (int it = 0; it < 8; ++it) {
            int idx = it * 512 + tid;
            int row = idx >> 6, c4 = idx & 63;
            bf16x4 o;
            o[0] = (bf16)xr[it].x; o[1] = (bf16)xr[it].y;
            o[2] = (bf16)xr[it].z; o[3] = (bf16)xr[it].w;
            *(bf16x4*)(xs + row * 512 + ((c4 * 8) ^ ((row & 7) << 4))) = o;
        }
    }
    __syncthreads();

    // identity B-fragment for the transpose-MFMA: B[k][col] = (k==col)
    bf16x4 iden;
    #pragma unroll
    for (int j = 0; j < 4; ++j) iden[j] = (bf16)((4 * g + j == c) ? 1.0f : 0.0f);

    bf16x4 qf[4][2];   // [qt][ct]  B-frag for scores (dies as qt advances)
    bf16x4 kf[4][2];   // [kt][ct]  A-frag for scores
    bf16x4 pB[4][4];   // [qt][kt]  softmax out == PV B-frag (parks thru V)
    bf16x4 vf[2][4];   // [dt][kt]  A-frag for PV
    bf16x4 ob[2][4];   // [dt][qt]  attn-out frags

    // ---- pass Q: BK=64, 4-wide weight batches ----
    {
        f32x4 acc[2][4];
        #pragma unroll
        for (int ni = 0; ni < 2; ++ni)
            #pragma unroll
            for (int mi = 0; mi < 4; ++mi)
                acc[ni][mi] = (f32x4){0.f, 0.f, 0.f, 0.f};
        #pragma unroll
        for (int k2 = 0; k2 < 4; ++k2) {
            bf16x8 bb[2][2];   // [ni][half]
            #pragma unroll
            for (int ni = 0; ni < 2; ++ni)
                #pragma unroll
                for (int hf = 0; hf < 2; ++hf)
                    bb[ni][hf] = *(const bf16x8*)(wt_qkv + (h * 32 + ni * 16 + c) * 256
                                                  + k2 * 64 + hf * 32 + g * 8);
            bf16x8 a[2][4];    // [half][mi]
            #pragma unroll
            for (int hf = 0; hf < 2; ++hf)
                #pragma unroll
                for (int mi = 0; mi < 4; ++mi) {
                    int row = mi * 16 + c;
                    a[hf][mi] = *(const bf16x8*)(xs + row * 512
                                 + ((k2 * 128 + hf * 64 + g * 16) ^ ((row & 7) << 4)));
                }
            #pragma unroll
            for (int hf = 0; hf < 2; ++hf)
                #pragma unroll
                for (int ni = 0; ni < 2; ++ni)
                    #pragma unroll
                    for (int mi = 0; mi < 4; ++mi)
                        acc[ni][mi] = __builtin_amdgcn_mfma_f32_16x16x32_bf16(a[hf][mi], bb[ni][hf], acc[ni][mi], 0, 0, 0);
        }
        #pragma unroll
        for (int ni = 0; ni < 2; ++ni) {
            float bias = qkv_b[h * 32 + ni * 16 + c] * SCALE_Q;
            #pragma unroll
            for (int mi = 0; mi < 4; ++mi) {
                bf16x4 in;
                #pragma unroll
                for (int r = 0; r < 4; ++r) in[r] = (bf16)(acc[ni][mi][r] + bias);
                f32x4 t = mfma16(in, iden, (f32x4){0.f, 0.f, 0.f, 0.f});
                #pragma unroll
                for (int r = 0; r < 4; ++r) qf[mi][ni][r] = (bf16)t[r];
            }
        }
    }

    // ---- pass K ----
    {
        f32x4 acc[2][4];
        #pragma unroll
        for (int ni = 0; ni < 2; ++ni)
            #pragma unroll
            for (int mi = 0; mi < 4; ++mi)
                acc[ni][mi] = (f32x4){0.f, 0.f, 0.f, 0.f};
        #pragma unroll
        for (int k2 = 0; k2 < 4; ++k2) {
            bf16x8 bb[2][2];
            #pragma unroll
            for (int ni = 0; ni < 2; ++ni)
                #pragma unroll
                for (int hf = 0; hf < 2; ++hf)
                    bb[ni][hf] = *(const bf16x8*)(wt_qkv + (256 + h * 32 + ni * 16 + c) * 256
                                                  + k2 * 64 + hf * 32 + g * 8);
            bf16x8 a[2][4];
            #pragma unroll
            for (int hf = 0; hf < 2; ++hf)
                #pragma unroll
                for (int mi = 0; mi < 4; ++mi) {
                    int row = mi * 16 + c;
                    a[hf][mi] = *(const bf16x8*)(xs + row * 512
                                 + ((k2 * 128 + hf * 64 + g * 16) ^ ((row & 7) << 4)));
                }
            #pragma unroll
            for (int hf = 0; hf < 2; ++hf)
                #pragma unroll
                for (int ni = 0; ni < 2; ++ni)
                    #pragma unroll
                    for (int mi = 0; mi < 4; ++mi)
                        acc[ni][mi] = __builtin_amdgcn_mfma_f32_16x16x32_bf16(a[hf][mi], bb[ni][hf], acc[ni][mi], 0, 0, 0);
        }
        #pragma unroll
        for (int ni = 0; ni < 2; ++ni) {
            float bias = qkv_b[256 + h * 32 + ni * 16 + c];
            #pragma unroll
            for (int mi = 0; mi < 4; ++mi) {
                bf16x4 in;
                #pragma unroll
                for (int r = 0; r < 4; ++r) in[r] = (bf16)(acc[ni][mi][r] + bias);
                f32x4 t = mfma16(in, iden, (f32x4){0.f, 0.f, 0.f, 0.f});
                #pragma unroll
                for (int r = 0; r < 4; ++r) kf[mi][ni][r] = (bf16)t[r];
            }
        }
    }

    // ---- scores + softmax (per qt; qf dies, pB grows) ----
    {
        const float* sbh = sb + (size_t)h * 4096;
        const float* smw = sm + (size_t)(b & 63) * 4096;
        #pragma unroll
        for (int qt = 0; qt < 4; ++qt) {
            f32x4 sbv[4], smv[4];
            #pragma unroll
            for (int kt = 0; kt < 4; ++kt)
                sbv[kt] = *(const f32x4*)(sbh + (kt * 4 + qt) * 256 + lane * 4);
            #pragma unroll
            for (int kt = 0; kt < 4; ++kt)
                smv[kt] = *(const f32x4*)(smw + (kt * 4 + qt) * 256 + lane * 4);

            f32x4 sT[4];
            __builtin_amdgcn_s_setprio(1);
            #pragma unroll
            for (int kt = 0; kt < 4; ++kt) {
                sT[kt] = (f32x4){0.f, 0.f, 0.f, 0.f};
                sT[kt] = mfma16(kf[kt][0], qf[qt][0], sT[kt]);
                sT[kt] = mfma16(kf[kt][1], qf[qt][1], sT[kt]);
            }
            __builtin_amdgcn_s_setprio(0);
            #pragma unroll
            for (int kt = 0; kt < 4; ++kt)
                #pragma unroll
                for (int r = 0; r < 4; ++r)
                    sT[kt][r] += sbv[kt][r] + smv[kt][r];
            float m = sT[0][0];
            #pragma unroll
            for (int kt = 0; kt < 4; ++kt)
                #pragma unroll
                for (int r = 0; r < 4; ++r) m = fmaxf(m, sT[kt][r]);
            m = fmaxf(m, __shfl_xor(m, 16));
            m = fmaxf(m, __shfl_xor(m, 32));
            float sum = 0.f;
            #pragma unroll
            for (int kt = 0; kt < 4; ++kt)
                #pragma unroll
                for (int r = 0; r < 4; ++r) {
                    float e = __expf(sT[kt][r] - m);
                    sT[kt][r] = e;
                    sum += e;
                }
            sum += __shfl_xor(sum, 16);
            sum += __shfl_xor(sum, 32);
            float rs = 1.f / sum;
            #pragma unroll
            for (int kt = 0; kt < 4; ++kt)
                #pragma unroll
                for (int r = 0; r < 4; ++r) pB[qt][kt][r] = (bf16)(sT[kt][r] * rs);
        }
    }

    // ---- pass V (qf/kf free; pB parked) ----
    {
        f32x4 acc[2][4];
        #pragma unroll
        for (int dt = 0; dt < 2; ++dt)
            #pragma unroll
            for (int mi = 0; mi < 4; ++mi)
                acc[dt][mi] = (f32x4){0.f, 0.f, 0.f, 0.f};
        #pragma unroll
        for (int k2 = 0; k2 < 4; ++k2) {
            bf16x8 bb[2][2];
            #pragma unroll
            for (int dt = 0; dt < 2; ++dt)
                #pragma unroll
                for (int hf = 0; hf < 2; ++hf)
                    bb[dt][hf] = *(const bf16x8*)(wt_qkv + (512 + h * 32 + dt * 16 + c) * 256
                                                  + k2 * 64 + hf * 32 + g * 8);
            bf16x8 a[2][4];
            #pragma unroll
            for (int hf = 0; hf < 2; ++hf)
                #pragma unroll
                for (int mi = 0; mi < 4; ++mi) {
                    int row = mi * 16 + c;
                    a[hf][mi] = *(const bf16x8*)(xs + row * 512
                                 + ((k2 * 128 + hf * 64 + g * 16) ^ ((row & 7) << 4)));
                }
            #pragma unroll
            for (int hf = 0; hf < 2; ++hf)
                #pragma unroll
                for (int dt = 0; dt < 2; ++dt)
                    #pragma unroll
                    for (int mi = 0; mi < 4; ++mi)
                        acc[dt][mi] = __builtin_amdgcn_mfma_f32_16x16x32_bf16(a[hf][mi], bb[dt][hf], acc[dt][mi], 0, 0, 0);
        }
        #pragma unroll
        for (int dt = 0; dt < 2; ++dt) {
            float vb = qkv_b[512 + h * 32 + dt * 16 + c];
            #pragma unroll
            for (int kt = 0; kt < 4; ++kt)
                #pragma unroll
                for (int r = 0; r < 4; ++r) vf[dt][kt][r] = (bf16)(acc[dt][kt][r] + vb);
        }
    }

    // ---- PV: ob[dt][qt] = sum_kt vf[dt][kt] x pB[qt][kt] ----
    __builtin_amdgcn_s_setprio(1);
    #pragma unroll
    for (int qt = 0; qt < 4; ++qt) {
        #pragma unroll
        for (int dt = 0; dt < 2; ++dt) {
            f32x4 oT = (f32x4){0.f, 0.f, 0.f, 0.f};
            #pragma unroll
            for (int kt = 0; kt < 4; ++kt)
                oT = mfma16(vf[dt][kt], pB[qt][kt], oT);
            #pragma unroll
            for (int r = 0; r < 4; ++r) ob[dt][qt][r] = (bf16)oT[r];
        }
    }
    __builtin_amdgcn_s_setprio(0);
    __syncthreads();   // all xs reads done (V-pass was last)

    // ---- write attn-out -> xs ----
    #pragma unroll
    for (int qt = 0; qt < 4; ++qt) {
        int row = qt * 16 + c;
        #pragma unroll
        for (int dt = 0; dt < 2; ++dt) {
            int cbyte = h * 64 + dt * 32 + g * 8;
            *(bf16x4*)(xs + row * 512 + (cbyte ^ ((row & 7) << 4))) = ob[dt][qt];
        }
    }
    __syncthreads();

    // ---- proj: BK=64, 4-wide weight batches, [64x256]@[256x32]/wave ----
    {
        f32x4 po[2][4];
        #pragma unroll
        for (int ni = 0; ni < 2; ++ni)
            #pragma unroll
            for (int mi = 0; mi < 4; ++mi)
                po[ni][mi] = (f32x4){0.f, 0.f, 0.f, 0.f};

        #pragma unroll
        for (int k2 = 0; k2 < 4; ++k2) {
            bf16x8 bw[2][2];
            #pragma unroll
            for (int ni = 0; ni < 2; ++ni)
                #pragma unroll
                for (int hf = 0; hf < 2; ++hf)
                    bw[ni][hf] = *(const bf16x8*)(wt_proj + (h * 32 + ni * 16 + c) * 256
                                                  + k2 * 64 + hf * 32 + g * 8);
            bf16x8 a[2][4];
            #pragma unroll
            for (int hf = 0; hf < 2; ++hf)
                #pragma unroll
                for (int mi = 0; mi < 4; ++mi) {
                    int row = mi * 16 + c;
                    a[hf][mi] = *(const bf16x8*)(xs + row * 512
                                 + ((k2 * 128 + hf * 64 + g * 16) ^ ((row & 7) << 4)));
                }
            #pragma unroll
            for (int hf = 0; hf < 2; ++hf)
                #pragma unroll
                for (int ni = 0; ni < 2; ++ni)
                    #pragma unroll
                    for (int mi = 0; mi < 4; ++mi)
                        po[ni][mi] = __builtin_amdgcn_mfma_f32_16x16x32_bf16(a[hf][mi], bw[ni][hf], po[ni][mi], 0, 0, 0);
        }
        float* outb = out + (size_t)b * (NTOK * 256);
        #pragma unroll
        for (int ni = 0; ni < 2; ++ni) {
            int col = h * 32 + ni * 16 + c;
            float pb = proj_b[col];
            #pragma unroll
            for (int mi = 0; mi < 4; ++mi) {
                #pragma unroll
                for (int r = 0; r < 4; ++r) {
                    int row = mi * 16 + g * 4 + r;
                    if (row < NTOK) outb[row * 256 + col] = po[ni][mi][r] + pb;
                }
            }
        }
    }
}

extern "C" void kernel_launch(void* const* d_in, const int* in_sizes, int n_in,
                              void* d_out, int out_size, void* d_ws, size_t ws_size,
                              hipStream_t stream) {
    const float* x          = (const float*)d_in[0];
    const float* mask       = (const float*)d_in[1];
    const float* qkv_w      = (const float*)d_in[2];
    const float* qkv_b      = (const float*)d_in[3];
    const float* proj_w     = (const float*)d_in[4];
    const float* proj_b     = (const float*)d_in[5];
    const float* bias_table = (const float*)d_in[6];
    const int*   rel_index  = (const int*)d_in[7];
    float* out = (float*)d_out;

    if (ws_size < WS_NEEDED) return;  // needs ~1.7 MB scratch

    char* ws = (char*)d_ws;
    bf16*  wt_qkv  = (bf16*)(ws + WT_QKV_OFF);
    bf16*  wt_proj = (bf16*)(ws + WT_PROJ_OFF);
    float* sbp     = (float*)(ws + SB_OFF);
    float* smp     = (float*)(ws + SM_OFF);

    prep_wqkv <<<768, 256, 0, stream>>>(qkv_w, wt_qkv);
    prep_wproj<<<256, 256, 0, stream>>>(proj_w, wt_proj);
    prep_sb   <<<128, 256, 0, stream>>>(bias_table, rel_index, sbp);
    prep_sm   <<<1024, 256, 0, stream>>>(mask, smp);

    fused_attn<<<4096, 512, 0, stream>>>(x, qkv_b, proj_b, wt_qkv, wt_proj, sbp, smp, out);
}

// Round 10
// 353.026 us; speedup vs baseline: 2.5939x; 1.0566x over previous
//
#include <hip/hip_runtime.h>
#include <hip/hip_bf16.h>

// ---------------------------------------------------------------------------
// Swin WindowAttention fused kernel, v10 = v9 + depth-2 software pipeline.
//   - All 4 GEMM passes: preload B/A(k2=0); body issues B/A(k2+1) BEFORE the
//     16 MFMAs of k2 -> one latency exposure per pass instead of four.
//   - Cross-phase prefetch chain: Q tail -> K's B(0)+A(0); scores tail ->
//     V's B(0)+A(0); post-PV -> proj's B(0) issued before the barriers.
//   - v9 base kept: 512thr/8-wave, 1 head/wave, phase order Q->K->scores->
//     V->PV (pB parks, not qf+kf), BK=64, sb/sm split tables, identity-MFMA
//     transposes, swapped-operand scores, setprio on attn MFMAs,
//     launch_bounds(512,2) (VGPR cap = 256/arg2 empirically).
// ---------------------------------------------------------------------------

#define NTOK 49
static constexpr float SCALE_Q = 0.17677669529663687f; // 32^-0.5

using bf16   = __bf16;
using bf16x4 = __attribute__((ext_vector_type(4))) __bf16;
using bf16x8 = __attribute__((ext_vector_type(8))) __bf16;
using short4v = __attribute__((ext_vector_type(4))) short;
using f32x4  = __attribute__((ext_vector_type(4))) float;

#define WT_QKV_OFF 0
#define WT_PROJ_OFF (768 * 256 * 2)
#define SB_OFF (WT_PROJ_OFF + 256 * 256 * 2)
#define SM_OFF (SB_OFF + 8 * 4096 * 4)
#define WS_NEEDED (SM_OFF + (size_t)64 * 4096 * 4)

// ---- 16x16x16 bf16 MFMA wrapper (builtin-name portability) ----
static __device__ __forceinline__ f32x4 mfma16(bf16x4 a, bf16x4 b, f32x4 c) {
#if __has_builtin(__builtin_amdgcn_mfma_f32_16x16x16_bf16)
    return __builtin_amdgcn_mfma_f32_16x16x16_bf16(a, b, c, 0, 0, 0);
#elif __has_builtin(__builtin_amdgcn_mfma_f32_16x16x16bf16_1k)
    return __builtin_amdgcn_mfma_f32_16x16x16bf16_1k(
        __builtin_bit_cast(short4v, a), __builtin_bit_cast(short4v, b), c, 0, 0, 0);
#elif __has_builtin(__builtin_amdgcn_mfma_f32_16x16x16_bf16_1k)
    return __builtin_amdgcn_mfma_f32_16x16x16_bf16_1k(
        __builtin_bit_cast(short4v, a), __builtin_bit_cast(short4v, b), c, 0, 0, 0);
#else
    asm volatile("v_mfma_f32_16x16x16_bf16 %0, %1, %2, %0\n\t"
                 "s_nop 7\n\ts_nop 7\n\ts_nop 1"
                 : "+v"(c) : "v"(a), "v"(b));
    return c;
#endif
}

static __device__ __forceinline__ bf16x8 ldsA(const char* xs, int row, int koff) {
    return *(const bf16x8*)(xs + row * 512 + (koff ^ ((row & 7) << 4)));
}
static __device__ __forceinline__ bf16x8 ldB(const bf16* wt, int ncol, int k2, int hf, int g) {
    return *(const bf16x8*)(wt + ncol * 256 + k2 * 64 + hf * 32 + g * 8);
}

// ---- precompute kernels ----
__global__ void prep_wqkv(const float* __restrict__ qkv_w, bf16* __restrict__ wt) {
    int idx = blockIdx.x * 256 + threadIdx.x;            // 768*256
    if (idx >= 768 * 256) return;
    int n = idx >> 8, k = idx & 255;
    float v = qkv_w[k * 768 + n];
    if (n < 256) v *= SCALE_Q;                           // fold q-scale
    wt[idx] = (bf16)v;                                   // wt[n][k]
}
__global__ void prep_wproj(const float* __restrict__ proj_w, bf16* __restrict__ wt) {
    int idx = blockIdx.x * 256 + threadIdx.x;            // 256*256
    if (idx >= 256 * 256) return;
    int n = idx >> 8, k = idx & 255;
    wt[idx] = (bf16)proj_w[k * 256 + n];                 // wt[n][k]
}
// sb[h][qp][lane][r]: rel-bias part for q=16qt+(lane&15), key=16kt+4*(lane>>4)+r
// (qp = kt*4+qt). -1e30 for key>=49 (pad); 0 for q>=49 (dead rows).
__global__ void prep_sb(const float* __restrict__ bias_table, const int* __restrict__ rel_index,
                        float* __restrict__ sb) {
    int idx = blockIdx.x * 256 + threadIdx.x;            // 8*4096
    if (idx >= 8 * 4096) return;
    int r    = idx & 3;
    int lane = (idx >> 2) & 63;
    int qp   = (idx >> 8) & 15;
    int h    = idx >> 12;
    int kt = qp >> 2, qt = qp & 3;
    int i = qt * 16 + (lane & 15);
    int j = kt * 16 + (lane >> 4) * 4 + r;
    float v;
    if (j >= NTOK)      v = -1e30f;
    else if (i >= NTOK) v = 0.0f;
    else v = bias_table[rel_index[i * 49 + j] * 8 + h];
    sb[idx] = v;
}
// sm[w][qp][lane][r]: window-mask part (0 on padded rows/cols).
__global__ void prep_sm(const float* __restrict__ mask, float* __restrict__ sm) {
    int idx = blockIdx.x * 256 + threadIdx.x;            // 64*4096
    if (idx >= 64 * 4096) return;
    int r    = idx & 3;
    int lane = (idx >> 2) & 63;
    int qp   = (idx >> 8) & 15;
    int w    = idx >> 12;
    int kt = qp >> 2, qt = qp & 3;
    int i = qt * 16 + (lane & 15);
    int j = kt * 16 + (lane >> 4) * 4 + r;
    sm[idx] = (i < NTOK && j < NTOK) ? mask[(w * 49 + i) * 49 + j] : 0.0f;
}

__global__ __launch_bounds__(512, 2) void fused_attn(
    const float* __restrict__ x,
    const float* __restrict__ qkv_b,
    const float* __restrict__ proj_b,
    const bf16* __restrict__ wt_qkv,
    const bf16* __restrict__ wt_proj,
    const float* __restrict__ sb,
    const float* __restrict__ sm,
    float* __restrict__ out)
{
    __shared__ char xs[32768];       // x tile (bf16, swizzled); later attn-out
    const int b    = blockIdx.x;
    const int tid  = threadIdx.x;
    const int lane = tid & 63;
    const int h    = tid >> 6;       // wave id == head
    const int c    = lane & 15;
    const int g    = lane >> 4;

    // ---- stage x -> xs: 8 reg-loads batched, then cvt+write ----
    {
        const float* xb = x + (size_t)b * (NTOK * 256);
        float4 xr[8];
        #pragma unroll
        for (int it = 0; it < 8; ++it) {
            int idx = it * 512 + tid;          // 64 rows x 64 float4-chunks
            int row = idx >> 6, c4 = idx & 63;
            xr[it] = make_float4(0.f, 0.f, 0.f, 0.f);
            if (row < NTOK) xr[it] = ((const float4*)xb)[row * 64 + c4];
        }
        #pragma unroll
        for (int it = 0; it < 8; ++it) {
            int idx = it * 512 + tid;
            int row = idx >> 6, c4 = idx & 63;
            bf16x4 o;
            o[0] = (bf16)xr[it].x; o[1] = (bf16)xr[it].y;
            o[2] = (bf16)xr[it].z; o[3] = (bf16)xr[it].w;
            *(bf16x4*)(xs + row * 512 + ((c4 * 8) ^ ((row & 7) << 4))) = o;
        }
    }
    __syncthreads();

    // identity B-fragment for the transpose-MFMA: B[k][col] = (k==col)
    bf16x4 iden;
    #pragma unroll
    for (int j = 0; j < 4; ++j) iden[j] = (bf16)((4 * g + j == c) ? 1.0f : 0.0f);

    bf16x4 qf[4][2];   // [qt][ct]  B-frag for scores (dies as qt advances)
    bf16x4 kf[4][2];   // [kt][ct]  A-frag for scores
    bf16x4 pB[4][4];   // [qt][kt]  softmax out == PV B-frag (parks thru V)
    bf16x4 vf[2][4];   // [dt][kt]  A-frag for PV
    bf16x4 ob[2][4];   // [dt][qt]  attn-out frags

    const int colQ = h * 32 + c;          // +0 / +16 for ni
    const int colK = 256 + h * 32 + c;
    const int colV = 512 + h * 32 + c;

    // pipeline registers
    bf16x8 bcur[2][2], bnxt[2][2];        // [ni][hf]
    bf16x8 acur[2][4], anxt[2][4];        // [hf][mi]

    // ---- preload Q(k2=0) ----
    #pragma unroll
    for (int ni = 0; ni < 2; ++ni)
        #pragma unroll
        for (int hf = 0; hf < 2; ++hf)
            bcur[ni][hf] = ldB(wt_qkv, colQ + ni * 16, 0, hf, g);
    #pragma unroll
    for (int hf = 0; hf < 2; ++hf)
        #pragma unroll
        for (int mi = 0; mi < 4; ++mi)
            acur[hf][mi] = ldsA(xs, mi * 16 + c, hf * 64 + g * 16);

    // ---- pass Q (pipelined; tail prefetches K(0)) ----
    {
        f32x4 acc[2][4];
        #pragma unroll
        for (int ni = 0; ni < 2; ++ni)
            #pragma unroll
            for (int mi = 0; mi < 4; ++mi)
                acc[ni][mi] = (f32x4){0.f, 0.f, 0.f, 0.f};
        #pragma unroll
        for (int k2 = 0; k2 < 4; ++k2) {
            if (k2 < 3) {
                #pragma unroll
                for (int ni = 0; ni < 2; ++ni)
                    #pragma unroll
                    for (int hf = 0; hf < 2; ++hf)
                        bnxt[ni][hf] = ldB(wt_qkv, colQ + ni * 16, k2 + 1, hf, g);
                #pragma unroll
                for (int hf = 0; hf < 2; ++hf)
                    #pragma unroll
                    for (int mi = 0; mi < 4; ++mi)
                        anxt[hf][mi] = ldsA(xs, mi * 16 + c, (k2 + 1) * 128 + hf * 64 + g * 16);
            } else {   // cross-phase: K's k2=0
                #pragma unroll
                for (int ni = 0; ni < 2; ++ni)
                    #pragma unroll
                    for (int hf = 0; hf < 2; ++hf)
                        bnxt[ni][hf] = ldB(wt_qkv, colK + ni * 16, 0, hf, g);
                #pragma unroll
                for (int hf = 0; hf < 2; ++hf)
                    #pragma unroll
                    for (int mi = 0; mi < 4; ++mi)
                        anxt[hf][mi] = ldsA(xs, mi * 16 + c, hf * 64 + g * 16);
            }
            #pragma unroll
            for (int hf = 0; hf < 2; ++hf)
                #pragma unroll
                for (int ni = 0; ni < 2; ++ni)
                    #pragma unroll
                    for (int mi = 0; mi < 4; ++mi)
                        acc[ni][mi] = __builtin_amdgcn_mfma_f32_16x16x32_bf16(acur[hf][mi], bcur[ni][hf], acc[ni][mi], 0, 0, 0);
            #pragma unroll
            for (int ni = 0; ni < 2; ++ni)
                #pragma unroll
                for (int hf = 0; hf < 2; ++hf)
                    bcur[ni][hf] = bnxt[ni][hf];
            #pragma unroll
            for (int hf = 0; hf < 2; ++hf)
                #pragma unroll
                for (int mi = 0; mi < 4; ++mi)
                    acur[hf][mi] = anxt[hf][mi];
        }
        #pragma unroll
        for (int ni = 0; ni < 2; ++ni) {
            float bias = qkv_b[h * 32 + ni * 16 + c] * SCALE_Q;
            #pragma unroll
            for (int mi = 0; mi < 4; ++mi) {
                bf16x4 in;
                #pragma unroll
                for (int r = 0; r < 4; ++r) in[r] = (bf16)(acc[ni][mi][r] + bias);
                f32x4 t = mfma16(in, iden, (f32x4){0.f, 0.f, 0.f, 0.f});
                #pragma unroll
                for (int r = 0; r < 4; ++r) qf[mi][ni][r] = (bf16)t[r];
            }
        }
    }

    // ---- pass K (pipelined; bcur/acur hold K(0) already) ----
    {
        f32x4 acc[2][4];
        #pragma unroll
        for (int ni = 0; ni < 2; ++ni)
            #pragma unroll
            for (int mi = 0; mi < 4; ++mi)
                acc[ni][mi] = (f32x4){0.f, 0.f, 0.f, 0.f};
        #pragma unroll
        for (int k2 = 0; k2 < 4; ++k2) {
            if (k2 < 3) {
                #pragma unroll
                for (int ni = 0; ni < 2; ++ni)
                    #pragma unroll
                    for (int hf = 0; hf < 2; ++hf)
                        bnxt[ni][hf] = ldB(wt_qkv, colK + ni * 16, k2 + 1, hf, g);
                #pragma unroll
                for (int hf = 0; hf < 2; ++hf)
                    #pragma unroll
                    for (int mi = 0; mi < 4; ++mi)
                        anxt[hf][mi] = ldsA(xs, mi * 16 + c, (k2 + 1) * 128 + hf * 64 + g * 16);
            }
            #pragma unroll
            for (int hf = 0; hf < 2; ++hf)
                #pragma unroll
                for (int ni = 0; ni < 2; ++ni)
                    #pragma unroll
                    for (int mi = 0; mi < 4; ++mi)
                        acc[ni][mi] = __builtin_amdgcn_mfma_f32_16x16x32_bf16(acur[hf][mi], bcur[ni][hf], acc[ni][mi], 0, 0, 0);
            if (k2 < 3) {
                #pragma unroll
                for (int ni = 0; ni < 2; ++ni)
                    #pragma unroll
                    for (int hf = 0; hf < 2; ++hf)
                        bcur[ni][hf] = bnxt[ni][hf];
                #pragma unroll
                for (int hf = 0; hf < 2; ++hf)
                    #pragma unroll
                    for (int mi = 0; mi < 4; ++mi)
                        acur[hf][mi] = anxt[hf][mi];
            }
        }
        #pragma unroll
        for (int ni = 0; ni < 2; ++ni) {
            float bias = qkv_b[256 + h * 32 + ni * 16 + c];
            #pragma unroll
            for (int mi = 0; mi < 4; ++mi) {
                bf16x4 in;
                #pragma unroll
                for (int r = 0; r < 4; ++r) in[r] = (bf16)(acc[ni][mi][r] + bias);
                f32x4 t = mfma16(in, iden, (f32x4){0.f, 0.f, 0.f, 0.f});
                #pragma unroll
                for (int r = 0; r < 4; ++r) kf[mi][ni][r] = (bf16)t[r];
            }
        }
    }

    // ---- scores + softmax (per qt; last qt prefetches V(0)) ----
    {
        const float* sbh = sb + (size_t)h * 4096;
        const float* smw = sm + (size_t)(b & 63) * 4096;
        #pragma unroll
        for (int qt = 0; qt < 4; ++qt) {
            f32x4 sbv[4], smv[4];
            #pragma unroll
            for (int kt = 0; kt < 4; ++kt)
                sbv[kt] = *(const f32x4*)(sbh + (kt * 4 + qt) * 256 + lane * 4);
            #pragma unroll
            for (int kt = 0; kt < 4; ++kt)
                smv[kt] = *(const f32x4*)(smw + (kt * 4 + qt) * 256 + lane * 4);

            f32x4 sT[4];
            __builtin_amdgcn_s_setprio(1);
            #pragma unroll
            for (int kt = 0; kt < 4; ++kt) {
                sT[kt] = (f32x4){0.f, 0.f, 0.f, 0.f};
                sT[kt] = mfma16(kf[kt][0], qf[qt][0], sT[kt]);
                sT[kt] = mfma16(kf[kt][1], qf[qt][1], sT[kt]);
            }
            __builtin_amdgcn_s_setprio(0);
            if (qt == 3) {   // prefetch V's k2=0 under the softmax tail
                #pragma unroll
                for (int ni = 0; ni < 2; ++ni)
                    #pragma unroll
                    for (int hf = 0; hf < 2; ++hf)
                        bcur[ni][hf] = ldB(wt_qkv, colV + ni * 16, 0, hf, g);
                #pragma unroll
                for (int hf = 0; hf < 2; ++hf)
                    #pragma unroll
                    for (int mi = 0; mi < 4; ++mi)
                        acur[hf][mi] = ldsA(xs, mi * 16 + c, hf * 64 + g * 16);
            }
            #pragma unroll
            for (int kt = 0; kt < 4; ++kt)
                #pragma unroll
                for (int r = 0; r < 4; ++r)
                    sT[kt][r] += sbv[kt][r] + smv[kt][r];
            float m = sT[0][0];
            #pragma unroll
            for (int kt = 0; kt < 4; ++kt)
                #pragma unroll
                for (int r = 0; r < 4; ++r) m = fmaxf(m, sT[kt][r]);
            m = fmaxf(m, __shfl_xor(m, 16));
            m = fmaxf(m, __shfl_xor(m, 32));
            float sum = 0.f;
            #pragma unroll
            for (int kt = 0; kt < 4; ++kt)
                #pragma unroll
                for (int r = 0; r < 4; ++r) {
                    float e = __expf(sT[kt][r] - m);
                    sT[kt][r] = e;
                    sum += e;
                }
            sum += __shfl_xor(sum, 16);
            sum += __shfl_xor(sum, 32);
            float rs = 1.f / sum;
            #pragma unroll
            for (int kt = 0; kt < 4; ++kt)
                #pragma unroll
                for (int r = 0; r < 4; ++r) pB[qt][kt][r] = (bf16)(sT[kt][r] * rs);
        }
    }

    // ---- pass V (pipelined; bcur/acur hold V(0)) ----
    {
        f32x4 acc[2][4];
        #pragma unroll
        for (int dt = 0; dt < 2; ++dt)
            #pragma unroll
            for (int mi = 0; mi < 4; ++mi)
                acc[dt][mi] = (f32x4){0.f, 0.f, 0.f, 0.f};
        #pragma unroll
        for (int k2 = 0; k2 < 4; ++k2) {
            if (k2 < 3) {
                #pragma unroll
                for (int dt = 0; dt < 2; ++dt)
                    #pragma unroll
                    for (int hf = 0; hf < 2; ++hf)
                        bnxt[dt][hf] = ldB(wt_qkv, colV + dt * 16, k2 + 1, hf, g);
                #pragma unroll
                for (int hf = 0; hf < 2; ++hf)
                    #pragma unroll
                    for (int mi = 0; mi < 4; ++mi)
                        anxt[hf][mi] = ldsA(xs, mi * 16 + c, (k2 + 1) * 128 + hf * 64 + g * 16);
            }
            #pragma unroll
            for (int hf = 0; hf < 2; ++hf)
                #pragma unroll
                for (int dt = 0; dt < 2; ++dt)
                    #pragma unroll
                    for (int mi = 0; mi < 4; ++mi)
                        acc[dt][mi] = __builtin_amdgcn_mfma_f32_16x16x32_bf16(acur[hf][mi], bcur[dt][hf], acc[dt][mi], 0, 0, 0);
            if (k2 < 3) {
                #pragma unroll
                for (int dt = 0; dt < 2; ++dt)
                    #pragma unroll
                    for (int hf = 0; hf < 2; ++hf)
                        bcur[dt][hf] = bnxt[dt][hf];
                #pragma unroll
                for (int hf = 0; hf < 2; ++hf)
                    #pragma unroll
                    for (int mi = 0; mi < 4; ++mi)
                        acur[hf][mi] = anxt[hf][mi];
            }
        }
        #pragma unroll
        for (int dt = 0; dt < 2; ++dt) {
            float vb = qkv_b[512 + h * 32 + dt * 16 + c];
            #pragma unroll
            for (int kt = 0; kt < 4; ++kt)
                #pragma unroll
                for (int r = 0; r < 4; ++r) vf[dt][kt][r] = (bf16)(acc[dt][kt][r] + vb);
        }
    }

    // ---- PV: ob[dt][qt] = sum_kt vf[dt][kt] x pB[qt][kt] ----
    __builtin_amdgcn_s_setprio(1);
    #pragma unroll
    for (int qt = 0; qt < 4; ++qt) {
        #pragma unroll
        for (int dt = 0; dt < 2; ++dt) {
            f32x4 oT = (f32x4){0.f, 0.f, 0.f, 0.f};
            #pragma unroll
            for (int kt = 0; kt < 4; ++kt)
                oT = mfma16(vf[dt][kt], pB[qt][kt], oT);
            #pragma unroll
            for (int r = 0; r < 4; ++r) ob[dt][qt][r] = (bf16)oT[r];
        }
    }
    __builtin_amdgcn_s_setprio(0);

    // prefetch proj's B(0) before the barriers (global load, no xs dep)
    #pragma unroll
    for (int ni = 0; ni < 2; ++ni)
        #pragma unroll
        for (int hf = 0; hf < 2; ++hf)
            bcur[ni][hf] = ldB(wt_proj, h * 32 + ni * 16 + c, 0, hf, g);

    __syncthreads();   // all xs reads done (V-pass was last)

    // ---- write attn-out -> xs ----
    #pragma unroll
    for (int qt = 0; qt < 4; ++qt) {
        int row = qt * 16 + c;
        #pragma unroll
        for (int dt = 0; dt < 2; ++dt) {
            int cbyte = h * 64 + dt * 32 + g * 8;
            *(bf16x4*)(xs + row * 512 + (cbyte ^ ((row & 7) << 4))) = ob[dt][qt];
        }
    }
    __syncthreads();

    // ---- proj (pipelined; bcur holds proj(0); A from fresh xs) ----
    {
        f32x4 po[2][4];
        #pragma unroll
        for (int ni = 0; ni < 2; ++ni)
            #pragma unroll
            for (int mi = 0; mi < 4; ++mi)
                po[ni][mi] = (f32x4){0.f, 0.f, 0.f, 0.f};

        #pragma unroll
        for (int hf = 0; hf < 2; ++hf)
            #pragma unroll
            for (int mi = 0; mi < 4; ++mi)
                acur[hf][mi] = ldsA(xs, mi * 16 + c, hf * 64 + g * 16);

        #pragma unroll
        for (int k2 = 0; k2 < 4; ++k2) {
            if (k2 < 3) {
                #pragma unroll
                for (int ni = 0; ni < 2; ++ni)
                    #pragma unroll
                    for (int hf = 0; hf < 2; ++hf)
                        bnxt[ni][hf] = ldB(wt_proj, h * 32 + ni * 16 + c, k2 + 1, hf, g);
                #pragma unroll
                for (int hf = 0; hf < 2; ++hf)
                    #pragma unroll
                    for (int mi = 0; mi < 4; ++mi)
                        anxt[hf][mi] = ldsA(xs, mi * 16 + c, (k2 + 1) * 128 + hf * 64 + g * 16);
            }
            #pragma unroll
            for (int hf = 0; hf < 2; ++hf)
                #pragma unroll
                for (int ni = 0; ni < 2; ++ni)
                    #pragma unroll
                    for (int mi = 0; mi < 4; ++mi)
                        po[ni][mi] = __builtin_amdgcn_mfma_f32_16x16x32_bf16(acur[hf][mi], bcur[ni][hf], po[ni][mi], 0, 0, 0);
            if (k2 < 3) {
                #pragma unroll
                for (int ni = 0; ni < 2; ++ni)
                    #pragma unroll
                    for (int hf = 0; hf < 2; ++hf)
                        bcur[ni][hf] = bnxt[ni][hf];
                #pragma unroll
                for (int hf = 0; hf < 2; ++hf)
                    #pragma unroll
                    for (int mi = 0; mi < 4; ++mi)
                        acur[hf][mi] = anxt[hf][mi];
            }
        }
        float* outb = out + (size_t)b * (NTOK * 256);
        #pragma unroll
        for (int ni = 0; ni < 2; ++ni) {
            int col = h * 32 + ni * 16 + c;
            float pb = proj_b[col];
            #pragma unroll
            for (int mi = 0; mi < 4; ++mi) {
                #pragma unroll
                for (int r = 0; r < 4; ++r) {
                    int row = mi * 16 + g * 4 + r;
                    if (row < NTOK) outb[row * 256 + col] = po[ni][mi][r] + pb;
                }
            }
        }
    }
}

extern "C" void kernel_launch(void* const* d_in, const int* in_sizes, int n_in,
                              void* d_out, int out_size, void* d_ws, size_t ws_size,
                              hipStream_t stream) {
    const float* x          = (const float*)d_in[0];
    const float* mask       = (const float*)d_in[1];
    const float* qkv_w      = (const float*)d_in[2];
    const float* qkv_b      = (const float*)d_in[3];
    const float* proj_w     = (const float*)d_in[4];
    const float* proj_b     = (const float*)d_in[5];
    const float* bias_table = (const float*)d_in[6];
    const int*   rel_index  = (const int*)d_in[7];
    float* out = (float*)d_out;

    if (ws_size < WS_NEEDED) return;  // needs ~1.7 MB scratch

    char* ws = (char*)d_ws;
    bf16*  wt_qkv  = (bf16*)(ws + WT_QKV_OFF);
    bf16*  wt_proj = (bf16*)(ws + WT_PROJ_OFF);
    float* sbp     = (float*)(ws + SB_OFF);
    float* smp     = (float*)(ws + SM_OFF);

    prep_wqkv <<<768, 256, 0, stream>>>(qkv_w, wt_qkv);
    prep_wproj<<<256, 256, 0, stream>>>(proj_w, wt_proj);
    prep_sb   <<<128, 256, 0, stream>>>(bias_table, rel_index, sbp);
    prep_sm   <<<1024, 256, 0, stream>>>(mask, smp);

    fused_attn<<<4096, 512, 0, stream>>>(x, qkv_b, proj_b, wt_qkv, wt_proj, sbp, smp, out);
}